// Round 1
// baseline (199.992 us; speedup 1.0000x reference)
//
#include <hip/hip_runtime.h>
#include <hip/hip_bf16.h>

// ContactLoss: Möller–Trumbore parity ray-cast (x2) + nearest-neighbor anchors
// + masked tanh means. All fp32, fp-contract OFF to bit-match numpy reference.

#define RX 0.4395064455f
#define RY 0.617598629942f
#define RZ 0.652231566745f

// ---------------------------------------------------------------------------
// Precompute per-triangle data: {v0.xyz, invdet}, {e1.xyz, flag}, {e2.xyz,0},
// {pvec.xyz,0}.  flag = (!parallel) && tri_valid.
// ---------------------------------------------------------------------------
__global__ void tri_pre(const float* __restrict__ verts, const int* __restrict__ faces,
                        const int* __restrict__ splits, int Nv, int T, int total,
                        float4* __restrict__ out) {
#pragma clang fp contract(off)
    int idx = blockIdx.x * blockDim.x + threadIdx.x;
    if (idx >= total) return;
    int b = idx / T;
    int t = idx - b * T;
    const int* f = faces + (size_t)idx * 3;
    const float* vb = verts + (size_t)b * Nv * 3;
    int i0 = f[0], i1 = f[1], i2 = f[2];
    float v0x = vb[i0*3+0], v0y = vb[i0*3+1], v0z = vb[i0*3+2];
    float v1x = vb[i1*3+0], v1y = vb[i1*3+1], v1z = vb[i1*3+2];
    float v2x = vb[i2*3+0], v2y = vb[i2*3+1], v2z = vb[i2*3+2];
    float e1x = v1x - v0x, e1y = v1y - v0y, e1z = v1z - v0z;
    float e2x = v2x - v0x, e2y = v2y - v0y, e2z = v2z - v0z;
    // pvec = cross(RAY_DIR, e2)
    float px = RY*e2z - RZ*e2y;
    float py = RZ*e2x - RX*e2z;
    float pz = RX*e2y - RY*e2x;
    float det = (e1x*px + e1y*py) + e1z*pz;       // ((a+b)+c) like np.sum
    float invdet = 1.0f / (det + 1e-8f);          // 0.1*TOL, IEEE div
    bool valid = !(fabsf(det) < 1e-7f);
    if (splits) valid = valid && (t < splits[b]);
    float4* o = out + (size_t)idx * 4;
    o[0] = make_float4(v0x, v0y, v0z, invdet);
    o[1] = make_float4(e1x, e1y, e1z, valid ? 1.0f : 0.0f);
    o[2] = make_float4(e2x, e2y, e2z, 0.0f);
    o[3] = make_float4(px,  py,  pz,  0.0f);
}

// ---------------------------------------------------------------------------
// Ray cast: thread = triangle (data in VGPRs), uniform loop over a point
// group (coords become scalar loads). Per point: ballot+popc per wave, one
// atomicAdd into hits[b*P+p].
// ---------------------------------------------------------------------------
__global__ void raycast(const float* __restrict__ pts, const float4* __restrict__ tri,
                        const int* __restrict__ psplits, int P, int Pg,
                        int T, const int* __restrict__ tsplits,
                        int* __restrict__ hits) {
#pragma clang fp contract(off)
    const int b = blockIdx.z;
    const int tlim = tsplits ? min(T, tsplits[b]) : T;
    if ((int)(blockIdx.y * blockDim.x) >= tlim) return;  // whole block invalid
    const int t = blockIdx.y * blockDim.x + threadIdx.x;

    float4 f0 = make_float4(0.f,0.f,0.f,0.f);
    float4 f1 = f0, f2 = f0, f3 = f0;                    // flag=0 for inactive
    if (t < tlim) {
        const float4* tp = tri + ((size_t)(b * T + t)) * 4;
        f0 = tp[0]; f1 = tp[1]; f2 = tp[2]; f3 = tp[3];
    }

    const int plim = psplits ? min(P, psplits[b]) : P;
    int p0 = blockIdx.x * Pg;
    int p1 = min(p0 + Pg, plim);
    const float* pb = pts + (size_t)b * P * 3;
    int* hb = hits + (size_t)b * P;
    const int lane = threadIdx.x & 63;

    for (int p = p0; p < p1; ++p) {
        float qx = pb[p*3+0], qy = pb[p*3+1], qz = pb[p*3+2];   // uniform
        float tvx = qx - f0.x, tvy = qy - f0.y, tvz = qz - f0.z;
        float u  = ((tvx*f3.x + tvy*f3.y) + tvz*f3.z) * f0.w;
        float qvx = tvy*f1.z - tvz*f1.y;
        float qvy = tvz*f1.x - tvx*f1.z;
        float qvz = tvx*f1.y - tvy*f1.x;
        float v  = ((qvx*RX + qvy*RY) + qvz*RZ) * f0.w;
        float tt = ((f2.x*qvx + f2.y*qvy) + f2.z*qvz) * f0.w;
        bool hit = (u > 0.0f) && (u < 1.0f) && (v > 0.0f) &&
                   ((u + v) < 1.0f) && (tt > 1e-7f) && (f1.w != 0.0f);
        unsigned long long m = __ballot(hit);
        if (lane == 0 && m) atomicAdd(&hb[p], (int)__popcll(m));
    }
}

// ---------------------------------------------------------------------------
// Wave-per-hand-vertex argmin over valid obj verts; anchor = |closest - hv|.
// Packed (dist_bits<<32)|idx min => first-occurrence tie-break like np.argmin.
// ---------------------------------------------------------------------------
__global__ void hand_min(const float* __restrict__ hand_verts,
                         const float* __restrict__ obj_verts,
                         const int* __restrict__ ovsplit,
                         int Nh, int No, int B,
                         float* __restrict__ anchor_h) {
#pragma clang fp contract(off)
    int w = (blockIdx.x * blockDim.x + threadIdx.x) >> 6;
    int lane = threadIdx.x & 63;
    if (w >= B * Nh) return;
    int b = w / Nh, n = w - b * Nh;
    const float* hv = hand_verts + ((size_t)b * Nh + n) * 3;
    float hx = hv[0], hy = hv[1], hz = hv[2];
    float rx = (hx*hx + hy*hy) + hz*hz;
    int split = ovsplit[b];
    const float* ob = obj_verts + (size_t)b * No * 3;
    unsigned long long best = ~0ull;
    for (int m = lane; m < split; m += 64) {
        float ox = ob[m*3+0], oy = ob[m*3+1], oz = ob[m*3+2];
        float ry = (ox*ox + oy*oy) + oz*oz;
        float zz = (hx*ox + hy*oy) + hz*oz;
        float d = (rx + ry) - 2.0f * zz;
        unsigned long long e = ((unsigned long long)__float_as_uint(d) << 32) | (unsigned)m;
        if (e < best) best = e;
    }
    for (int off = 32; off > 0; off >>= 1) {
        unsigned long long o = __shfl_xor(best, off, 64);
        if (o < best) best = o;
    }
    if (lane == 0) {
        int idx = (best == ~0ull) ? 0 : (int)(best & 0xffffffffu);
        const float* cv = ob + (size_t)idx * 3;
        float dx = cv[0] - hx, dy = cv[1] - hy, dz = cv[2] - hz;
        anchor_h[(size_t)b * Nh + n] = sqrtf((dx*dx + dy*dy) + dz*dz);
    }
}

// Wave-per-obj-vertex (valid only) argmin over all hand verts.
__global__ void obj_min(const float* __restrict__ hand_verts,
                        const float* __restrict__ obj_verts,
                        const int* __restrict__ ovsplit,
                        int Nh, int No, int B,
                        float* __restrict__ anchor_o) {
#pragma clang fp contract(off)
    int w = (blockIdx.x * blockDim.x + threadIdx.x) >> 6;
    int lane = threadIdx.x & 63;
    if (w >= B * No) return;
    int b = w / No, m = w - b * No;
    if (m >= ovsplit[b]) return;
    const float* ov = obj_verts + ((size_t)b * No + m) * 3;
    float ox = ov[0], oy = ov[1], oz = ov[2];
    float ry = (ox*ox + oy*oy) + oz*oz;
    const float* hb = hand_verts + (size_t)b * Nh * 3;
    unsigned long long best = ~0ull;
    for (int n = lane; n < Nh; n += 64) {
        float hx = hb[n*3+0], hy = hb[n*3+1], hz = hb[n*3+2];
        float rx = (hx*hx + hy*hy) + hz*hz;
        float zz = (hx*ox + hy*oy) + hz*oz;
        float d = (rx + ry) - 2.0f * zz;
        unsigned long long e = ((unsigned long long)__float_as_uint(d) << 32) | (unsigned)n;
        if (e < best) best = e;
    }
    for (int off = 32; off > 0; off >>= 1) {
        unsigned long long o = __shfl_xor(best, off, 64);
        if (o < best) best = o;
    }
    if (lane == 0) {
        int idx = (best == ~0ull) ? 0 : (int)(best & 0xffffffffu);
        const float* cv = hb + (size_t)idx * 3;
        float dx = cv[0] - ox, dy = cv[1] - oy, dz = cv[2] - oz;
        anchor_o[(size_t)b * No + m] = sqrtf((dx*dx + dy*dy) + dz*dz);
    }
}

// ---------------------------------------------------------------------------
// Per-batch masked sums + row losses. partials[b*6] = {s_miss,c_miss,
// s_ph,c_ph,s_po,c_po}. Writes out[2+b] (missed_losses) and out[10+b]
// (penetr_losses).
// ---------------------------------------------------------------------------
__global__ void reduce_batch(const int* __restrict__ hits_hand, const int* __restrict__ hits_obj,
                             const float* __restrict__ anchor_h, const float* __restrict__ anchor_o,
                             const int* __restrict__ ovsplit, int Nh, int No,
                             float* __restrict__ partials, float* __restrict__ out) {
    int b = blockIdx.x, tid = threadIdx.x;
    float s0=0.f,s1=0.f,s2=0.f,s3=0.f,s4=0.f,s5=0.f;
    for (int n = tid; n < Nh; n += blockDim.x) {
        bool ext = (hits_hand[(size_t)b*Nh + n] & 1) == 0;
        float val = 25.0f * tanhf(anchor_h[(size_t)b*Nh + n] / 25.0f);
        if (ext) { s0 += val; s1 += 1.0f; } else { s2 += val; s3 += 1.0f; }
    }
    int split = ovsplit[b];
    for (int m = tid; m < split; m += blockDim.x) {
        if ((hits_obj[(size_t)b*No + m] & 1) != 0) {   // interior & valid
            s4 += 25.0f * tanhf(anchor_o[(size_t)b*No + m] / 25.0f);
            s5 += 1.0f;
        }
    }
    __shared__ float red[6][256];
    red[0][tid]=s0; red[1][tid]=s1; red[2][tid]=s2;
    red[3][tid]=s3; red[4][tid]=s4; red[5][tid]=s5;
    __syncthreads();
    for (int st = 128; st > 0; st >>= 1) {
        if (tid < st) {
            #pragma unroll
            for (int k = 0; k < 6; ++k) red[k][tid] += red[k][tid + st];
        }
        __syncthreads();
    }
    if (tid == 0) {
        float sm=red[0][0], cm=red[1][0], sph=red[2][0],
              cph=red[3][0], spo=red[4][0], cpo=red[5][0];
        out[2 + b]  = (cm  > 0.f) ? sm  / fmaxf(cm , 1.f) : 0.f;
        float ph    = (cph > 0.f) ? sph / fmaxf(cph, 1.f) : 0.f;
        float po    = (cpo > 0.f) ? spo / fmaxf(cpo, 1.f) : 0.f;
        out[10 + b] = ph + po;
        float* pp = partials + b * 6;
        pp[0]=sm; pp[1]=cm; pp[2]=sph; pp[3]=cph; pp[4]=spo; pp[5]=cpo;
    }
}

__global__ void finalize(const float* __restrict__ partials, int B, float* __restrict__ out) {
    if (threadIdx.x == 0 && blockIdx.x == 0) {
        float sm=0.f,cm=0.f,sph=0.f,cph=0.f,spo=0.f,cpo=0.f;
        for (int b = 0; b < B; ++b) {
            const float* pp = partials + b * 6;
            sm += pp[0]; cm += pp[1]; sph += pp[2];
            cph += pp[3]; spo += pp[4]; cpo += pp[5];
        }
        float missed = (cm  > 0.f) ? sm  / fmaxf(cm , 1.f) : 0.f;
        float ph     = (cph > 0.f) ? sph / fmaxf(cph, 1.f) : 0.f;
        float po     = (cpo > 0.f) ? spo / fmaxf(cpo, 1.f) : 0.f;
        out[0] = missed;
        out[1] = ph + po;
    }
}

// ---------------------------------------------------------------------------
extern "C" void kernel_launch(void* const* d_in, const int* in_sizes, int n_in,
                              void* d_out, int out_size, void* d_ws, size_t ws_size,
                              hipStream_t stream) {
    const float* hand_verts = (const float*)d_in[0];
    const int*   hand_faces = (const int*)d_in[1];
    const float* obj_verts  = (const float*)d_in[2];
    const int*   obj_faces  = (const int*)d_in[3];
    const int*   ovsplit    = (const int*)d_in[4];
    const int*   ofsplit    = (const int*)d_in[5];
    float* out = (float*)d_out;

    const int B  = in_sizes[4];
    const int Nh = in_sizes[0] / (3 * B);
    const int Fh = in_sizes[1] / (3 * B);
    const int No = in_sizes[2] / (3 * B);
    const int Fo = in_sizes[3] / (3 * B);

    char* ws = (char*)d_ws;
    size_t off = 0;
    auto alloc = [&](size_t bytes) -> void* {
        void* p = ws + off;
        off = (off + bytes + 255) & ~(size_t)255;
        return p;
    };
    float4* htri      = (float4*)alloc((size_t)B * Fh * 4 * sizeof(float4));
    float4* otri      = (float4*)alloc((size_t)B * Fo * 4 * sizeof(float4));
    int*    hits_obj  = (int*)   alloc((size_t)B * No * sizeof(int));
    int*    hits_hand = (int*)   alloc((size_t)B * Nh * sizeof(int));
    float*  anchor_h  = (float*) alloc((size_t)B * Nh * sizeof(float));
    float*  anchor_o  = (float*) alloc((size_t)B * No * sizeof(float));
    float*  partials  = (float*) alloc((size_t)B * 6 * sizeof(float));

    hipMemsetAsync(hits_obj,  0, (size_t)B * No * sizeof(int), stream);
    hipMemsetAsync(hits_hand, 0, (size_t)B * Nh * sizeof(int), stream);

    int tot_h = B * Fh;
    tri_pre<<<(tot_h + 255) / 256, 256, 0, stream>>>(hand_verts, hand_faces, nullptr,
                                                     Nh, Fh, tot_h, htri);
    int tot_o = B * Fo;
    tri_pre<<<(tot_o + 255) / 256, 256, 0, stream>>>(obj_verts, obj_faces, ofsplit,
                                                     No, Fo, tot_o, otri);

    const int PG = 128;  // points per block per pass
    dim3 gA((No + PG - 1) / PG, (Fh + 255) / 256, B);
    raycast<<<gA, 256, 0, stream>>>(obj_verts, htri, ovsplit, No, PG, Fh, nullptr, hits_obj);
    dim3 gB((Nh + PG - 1) / PG, (Fo + 255) / 256, B);
    raycast<<<gB, 256, 0, stream>>>(hand_verts, otri, nullptr, Nh, PG, Fo, ofsplit, hits_hand);

    int wavesH = B * Nh;
    hand_min<<<(wavesH * 64 + 255) / 256, 256, 0, stream>>>(hand_verts, obj_verts, ovsplit,
                                                            Nh, No, B, anchor_h);
    int wavesO = B * No;
    obj_min<<<(wavesO * 64 + 255) / 256, 256, 0, stream>>>(hand_verts, obj_verts, ovsplit,
                                                           Nh, No, B, anchor_o);

    reduce_batch<<<B, 256, 0, stream>>>(hits_hand, hits_obj, anchor_h, anchor_o,
                                        ovsplit, Nh, No, partials, out);
    finalize<<<1, 64, 0, stream>>>(partials, B, out);
}